// Round 3
// baseline (448.225 us; speedup 1.0000x reference)
//
#include <hip/hip_runtime.h>
#include <hip/hip_bf16.h>

#define N_NODES 8192
#define F_IN    128
#define F_OUT   64
#define N_EDGES 262144

typedef unsigned int   u32;
typedef unsigned short u16;

// ---------------------------------------------------------------------------
// Detect edge_index width: int64 => all odd 32-bit words zero (ids < 8192).
// eflag != 0  =>  int32.
// ---------------------------------------------------------------------------
__global__ __launch_bounds__(256) void detect_ei_kernel(const int* __restrict__ ei,
                                                        int* __restrict__ eflag) {
    int i = blockIdx.x * 256 + threadIdx.x;          // 8192 samples
    if (ei[2 * i + 1] != 0) atomicOr(eflag, 1);
}

// ---------------------------------------------------------------------------
// Detect x dtype (hedge; expected fp32). Low 16 bits of sampled u32 words,
// bf16-exponent-in-normal-range test. xdt = 1 => bf16, 0 => fp32.
// ---------------------------------------------------------------------------
__global__ __launch_bounds__(256) void detect_xdt_kernel(const u32* __restrict__ xw,
                                                         int* __restrict__ xdt) {
    __shared__ int cnt;
    if (threadIdx.x == 0) cnt = 0;
    __syncthreads();
    u32 w = xw[threadIdx.x * 64 + 1];
    u32 e = (w >> 7) & 0xFFu;
    if (e >= 100u && e <= 134u) atomicAdd(&cnt, 1);
    __syncthreads();
    if (threadIdx.x == 0) *xdt = (cnt > 128) ? 1 : 0;
}

// deg[d] = count of incoming edges (self loop added later as +1)
__global__ __launch_bounds__(256) void deg_kernel(const int* __restrict__ ei,
                                                  const int* __restrict__ eflagp,
                                                  int* __restrict__ deg) {
    int e = blockIdx.x * 256 + threadIdx.x;
    bool is64 = (*eflagp == 0);
    int d = is64 ? ei[2 * (N_EDGES + e)] : ei[N_EDGES + e];
    atomicAdd(&deg[d], 1);
}

// ---------------------------------------------------------------------------
// h = x^T W (fp32), dinv = rsqrt(deg+1), z = b + dinv^2 * h (self-loop folded).
// 65536 threads: og = id>>13 (uniform per block), n = id & 8191 (coalesced).
// ---------------------------------------------------------------------------
__global__ __launch_bounds__(256) void feat_kernel(
        const void* __restrict__ xv, const void* __restrict__ Wv,
        const void* __restrict__ bv, const int* __restrict__ xdtp,
        const int* __restrict__ deg,
        float* __restrict__ dinv,
        float* __restrict__ h,                  // [N][64]
        float* __restrict__ z)                  // [N][64]
{
    __shared__ float Wl[F_IN * F_OUT];          // 32 KB
    const bool isbf = (*xdtp != 0);
    int t = threadIdx.x;
    if (isbf) {
        const __hip_bfloat16* Wb = (const __hip_bfloat16*)Wv;
        for (int i = t; i < F_IN * F_OUT; i += 256) Wl[i] = (float)Wb[i];
    } else {
        const float* Wf = (const float*)Wv;
        for (int i = t; i < F_IN * F_OUT; i += 256) Wl[i] = Wf[i];
    }
    __syncthreads();

    int id = blockIdx.x * 256 + t;              // 0..65535
    int og = id >> 13;                          // 0..7, uniform within block
    int n  = id & (N_NODES - 1);

    float dv = rsqrtf((float)(deg[n] + 1));
    float acc[8] = {0.f,0.f,0.f,0.f,0.f,0.f,0.f,0.f};

    if (isbf) {
        const __hip_bfloat16* xb = (const __hip_bfloat16*)xv;
        for (int f = 0; f < F_IN; ++f) {
            float xval = (float)xb[f * N_NODES + n];
            const float4* w4 = (const float4*)&Wl[f * F_OUT + og * 8];
            float4 w0 = w4[0], w1 = w4[1];
            acc[0] += xval * w0.x; acc[1] += xval * w0.y;
            acc[2] += xval * w0.z; acc[3] += xval * w0.w;
            acc[4] += xval * w1.x; acc[5] += xval * w1.y;
            acc[6] += xval * w1.z; acc[7] += xval * w1.w;
        }
    } else {
        const float* xf = (const float*)xv;
        for (int f = 0; f < F_IN; ++f) {
            float xval = xf[f * N_NODES + n];
            const float4* w4 = (const float4*)&Wl[f * F_OUT + og * 8];
            float4 w0 = w4[0], w1 = w4[1];
            acc[0] += xval * w0.x; acc[1] += xval * w0.y;
            acc[2] += xval * w0.z; acc[3] += xval * w0.w;
            acc[4] += xval * w1.x; acc[5] += xval * w1.y;
            acc[6] += xval * w1.z; acc[7] += xval * w1.w;
        }
    }

    if (og == 0) dinv[n] = dv;
    float dv2 = dv * dv;

    float* hp = h + (size_t)n * 64 + og * 8;
    ((float4*)hp)[0] = make_float4(acc[0], acc[1], acc[2], acc[3]);
    ((float4*)hp)[1] = make_float4(acc[4], acc[5], acc[6], acc[7]);

    float bvals[8];
    if (isbf) {
        const __hip_bfloat16* bb = (const __hip_bfloat16*)bv;
        #pragma unroll
        for (int j = 0; j < 8; ++j) bvals[j] = (float)bb[og * 8 + j];
    } else {
        const float* bf = (const float*)bv;
        #pragma unroll
        for (int j = 0; j < 8; ++j) bvals[j] = bf[og * 8 + j];
    }
    float zb[8];
    #pragma unroll
    for (int j = 0; j < 8; ++j) zb[j] = bvals[j] + dv2 * acc[j];
    float* zp = z + (size_t)n * 64 + og * 8;
    ((float4*)zp)[0] = make_float4(zb[0], zb[1], zb[2], zb[3]);
    ((float4*)zp)[1] = make_float4(zb[4], zb[5], zb[6], zb[7]);
}

// ---------------------------------------------------------------------------
// z[dst] += dinv[src]*dinv[dst] * h[src] -- one 64-lane wave per edge.
// ---------------------------------------------------------------------------
__global__ __launch_bounds__(256) void scatter_kernel(
        const int* __restrict__ ei, const int* __restrict__ eflagp,
        const float* __restrict__ h, const float* __restrict__ dinv,
        float* __restrict__ z)
{
    int t = blockIdx.x * 256 + threadIdx.x;
    int e = t >> 6;
    int o = t & 63;
    bool is64 = (*eflagp == 0);
    int s = is64 ? ei[2 * e]             : ei[e];
    int d = is64 ? ei[2 * (N_EDGES + e)] : ei[N_EDGES + e];
    float nrm = dinv[s] * dinv[d];
    atomicAdd(&z[(size_t)d * 64 + o], nrm * h[(size_t)s * 64 + o]);
}

// ---------------------------------------------------------------------------
// out = sigmoid(z @ z^T), FP32 output. 128x128 tile / block, K=64 in LDS.
// ---------------------------------------------------------------------------
__global__ __launch_bounds__(256) void gemm_sig_kernel(
        const float* __restrict__ z, float* __restrict__ out)
{
    __shared__ float As[64][128];   // 32 KB
    __shared__ float Bs[64][128];   // 32 KB
    int t  = threadIdx.x;
    int i0 = blockIdx.x * 128;
    int j0 = blockIdx.y * 128;

    #pragma unroll
    for (int l = 0; l < 8; ++l) {
        int lin = l * 256 + t;
        int c = lin >> 7;           // float4 chunk of k (0..15)
        int r = lin & 127;          // row within tile
        float4 va = *(const float4*)(z + (size_t)(i0 + r) * 64 + c * 4);
        As[c * 4 + 0][r] = va.x; As[c * 4 + 1][r] = va.y;
        As[c * 4 + 2][r] = va.z; As[c * 4 + 3][r] = va.w;
        float4 vb = *(const float4*)(z + (size_t)(j0 + r) * 64 + c * 4);
        Bs[c * 4 + 0][r] = vb.x; Bs[c * 4 + 1][r] = vb.y;
        Bs[c * 4 + 2][r] = vb.z; Bs[c * 4 + 3][r] = vb.w;
    }
    __syncthreads();

    int tx = t & 15, ty = t >> 4;
    float acc[8][8] = {};

    #pragma unroll 4
    for (int k = 0; k < 64; ++k) {
        float4 a0 = *(const float4*)&As[k][ty * 8];
        float4 a1 = *(const float4*)&As[k][ty * 8 + 4];
        float4 b0 = *(const float4*)&Bs[k][tx * 8];
        float4 b1 = *(const float4*)&Bs[k][tx * 8 + 4];
        float av[8] = {a0.x,a0.y,a0.z,a0.w,a1.x,a1.y,a1.z,a1.w};
        float bw[8] = {b0.x,b0.y,b0.z,b0.w,b1.x,b1.y,b1.z,b1.w};
        #pragma unroll
        for (int ri = 0; ri < 8; ++ri)
            #pragma unroll
            for (int ci = 0; ci < 8; ++ci)
                acc[ri][ci] += av[ri] * bw[ci];
    }

    #pragma unroll
    for (int ri = 0; ri < 8; ++ri) {
        int row = i0 + ty * 8 + ri;
        float s[8];
        #pragma unroll
        for (int ci = 0; ci < 8; ++ci)
            s[ci] = 1.f / (1.f + __expf(-acc[ri][ci]));
        float* op = out + (size_t)row * N_NODES + j0 + tx * 8;
        ((float4*)op)[0] = make_float4(s[0], s[1], s[2], s[3]);
        ((float4*)op)[1] = make_float4(s[4], s[5], s[6], s[7]);
    }
}

// ---------------------------------------------------------------------------
extern "C" void kernel_launch(void* const* d_in, const int* in_sizes, int n_in,
                              void* d_out, int out_size, void* d_ws, size_t ws_size,
                              hipStream_t stream) {
    const void* x  = d_in[0];                 // fp32 [128][8192]
    const int*  ei = (const int*)d_in[1];     // int64 or int32 [2][262144]
    const void* W  = d_in[2];                 // fp32 [128][64]
    const void* b  = d_in[3];                 // fp32 [64]
    float* out = (float*)d_out;               // fp32 [8192][8192]

    char* ws = (char*)d_ws;
    int*   deg   = (int*)ws;                                    // 32 KB
    int*   eflag = (int*)(ws + 8192 * 4);                       // 4 B
    int*   xdt   = (int*)(ws + 8192 * 4 + 16);                  // 4 B
    float* dinv  = (float*)(ws + 8192 * 4 + 256);               // 32 KB
    float* h     = (float*)(ws + 8192 * 4 + 256 + 8192 * 4);    // 2 MB
    float* z     = (float*)((char*)h + (size_t)N_NODES * 64 * 4); // 2 MB

    hipMemsetAsync(ws, 0, 8192 * 4 + 256, stream);              // deg + flags
    detect_ei_kernel<<<32, 256, 0, stream>>>(ei, eflag);
    detect_xdt_kernel<<<1, 256, 0, stream>>>((const u32*)x, xdt);
    deg_kernel<<<N_EDGES / 256, 256, 0, stream>>>(ei, eflag, deg);
    feat_kernel<<<256, 256, 0, stream>>>(x, W, b, xdt, deg, dinv, h, z);
    scatter_kernel<<<N_EDGES * 64 / 256, 256, 0, stream>>>(ei, eflag, h, dinv, z);
    gemm_sig_kernel<<<dim3(64, 64), 256, 0, stream>>>(z, out);
}